// Round 1
// baseline (3266.208 us; speedup 1.0000x reference)
//
#include <hip/hip_runtime.h>

#define LSZ 64
#define TILE 16

// Fused per-layer kernel:
//  - z_grid = A-parity-masked input tile (22x22 incl. halo-3, periodic wrap)
//  - h1 = tanh(conv1(z_grid))  over 20x20, 16 ch
//  - h2 = tanh(conv2(h1))      over 18x18, 16 ch
//  - logit = conv3(h2)         over 16x16
//  - B-parity sites: x *= sign(logit); A-sites copied through on layer 0 only.
// In-place across layers is safe: conv input never reads B-site *values*
// (masked to 0), and only B-sites are written.
__global__ __launch_bounds__(256, 2)
void discrete_flow_layer(const float* __restrict__ x_in,
                         float* __restrict__ x_out,
                         const float* __restrict__ W0,  // (3,3,1,16)
                         const float* __restrict__ B0,  // (16)
                         const float* __restrict__ W1,  // (3,3,16,16)
                         const float* __restrict__ B1,  // (16)
                         const float* __restrict__ W2,  // (3,3,16,1)
                         const float* __restrict__ B2,  // (1)
                         int parityA, int writeA)
{
    __shared__ float s_in[22 * 22];        // masked input tile
    __shared__ float s_h1[16 * 400];       // [ch][20*20] channel-major planes
    __shared__ float s_h2[16 * 324];       // [ch][18*18]
    __shared__ float s_w1[2304];           // [tap][cin][cout]
    __shared__ float s_w0[144];            // [tap][cout]
    __shared__ float s_w2[144];            // [tap][cin]
    __shared__ float s_b0[16];
    __shared__ float s_b1[16];

    const int tid = threadIdx.x;
    const int tile = blockIdx.x;               // 0..15 (4x4 tiles of 16x16)
    const int b    = blockIdx.y;               // batch index
    const int r0 = (tile >> 2) * TILE;
    const int c0 = (tile & 3) * TILE;
    const float* xb = x_in + (size_t)b * (LSZ * LSZ);

    // ---- stage input (22x22, wrap, A-parity mask) + weights ----
    for (int idx = tid; idx < 484; idx += 256) {
        int r = idx / 22, c = idx % 22;
        int gr = (r0 + r - 3) & 63;
        int gc = (c0 + c - 3) & 63;
        float v = xb[gr * 64 + gc];
        s_in[idx] = (((gr + gc) & 1) == parityA) ? v : 0.0f;
    }
    for (int idx = tid; idx < 2304; idx += 256) s_w1[idx] = W1[idx];
    if (tid < 144) { s_w0[tid] = W0[tid]; s_w2[tid] = W2[tid]; }
    if (tid < 16)  { s_b0[tid] = B0[tid]; s_b1[tid] = B1[tid]; }
    __syncthreads();

    // ---- conv1: 1 -> 16 over 20x20 (output abs coord r0-2+ry) ----
    for (int p = tid; p < 400; p += 256) {
        int ry = p / 20, rx = p % 20;
        float acc[16];
        #pragma unroll
        for (int c = 0; c < 16; ++c) acc[c] = s_b0[c];
        #pragma unroll
        for (int kh = 0; kh < 3; ++kh) {
            #pragma unroll
            for (int kw = 0; kw < 3; ++kw) {
                float v = s_in[(ry + kh) * 22 + rx + kw];
                const float* w = &s_w0[(kh * 3 + kw) * 16];
                #pragma unroll
                for (int c = 0; c < 16; ++c) acc[c] = fmaf(v, w[c], acc[c]);
            }
        }
        #pragma unroll
        for (int c = 0; c < 16; ++c) s_h1[c * 400 + p] = tanhf(acc[c]);
    }
    __syncthreads();

    // ---- conv2: 16 -> 16 over 18x18 (output abs coord r0-1+ry) ----
    for (int p = tid; p < 324; p += 256) {
        int ry = p / 18, rx = p % 18;
        float acc[16];
        #pragma unroll
        for (int c = 0; c < 16; ++c) acc[c] = s_b1[c];
        for (int tap = 0; tap < 9; ++tap) {
            int kh = tap / 3, kw = tap % 3;
            int hp = (ry + kh) * 20 + rx + kw;
            const float* w = &s_w1[tap * 256];
            #pragma unroll 4
            for (int ci = 0; ci < 16; ++ci) {
                float v = s_h1[ci * 400 + hp];
                #pragma unroll
                for (int co = 0; co < 16; ++co)
                    acc[co] = fmaf(v, w[ci * 16 + co], acc[co]);
            }
        }
        #pragma unroll
        for (int c = 0; c < 16; ++c) s_h2[c * 324 + p] = tanhf(acc[c]);
    }
    __syncthreads();

    // ---- conv3: 16 -> 1 over 16x16 + sign update ----
    {
        int p = tid;                           // exactly 256 positions
        int ry = p / 16, rx = p % 16;
        float acc = B2[0];
        for (int tap = 0; tap < 9; ++tap) {
            int kh = tap / 3, kw = tap % 3;
            int hp = (ry + kh) * 18 + rx + kw;
            const float* w = &s_w2[tap * 16];
            #pragma unroll
            for (int ci = 0; ci < 16; ++ci)
                acc = fmaf(s_h2[ci * 324 + hp], w[ci], acc);
        }
        int gr = r0 + ry, gc = c0 + rx;
        size_t site = (size_t)b * (LSZ * LSZ) + gr * 64 + gc;
        bool isB = (((gr + gc) & 1) != parityA);
        float xv = x_in[site];
        if (isB) {
            float m = (acc > 0.0f) ? 1.0f : ((acc < 0.0f) ? -1.0f : 0.0f);
            x_out[site] = xv * m;
        } else if (writeA) {
            x_out[site] = xv;
        }
    }
}

extern "C" void kernel_launch(void* const* d_in, const int* in_sizes, int n_in,
                              void* d_out, int out_size, void* d_ws, size_t ws_size,
                              hipStream_t stream) {
    const float* z  = (const float*)d_in[0];
    const float* W0 = (const float*)d_in[1];
    const float* B0 = (const float*)d_in[2];
    const float* W1 = (const float*)d_in[3];
    const float* B1 = (const float*)d_in[4];
    const float* W2 = (const float*)d_in[5];
    const float* B2 = (const float*)d_in[6];
    float* out = (float*)d_out;

    dim3 grid(16, 1024);
    for (int layer = 0; layer < 4; ++layer) {
        const float* xin = (layer == 0) ? z : out;
        int writeA = (layer == 0) ? 1 : 0;
        int parityA = layer & 1;               // 'even' layers: A = even parity
        discrete_flow_layer<<<grid, 256, 0, stream>>>(
            xin, out,
            W0 + layer * 144, B0 + layer * 16,
            W1 + layer * 2304, B1 + layer * 16,
            W2 + layer * 144, B2 + layer * 1,
            parityA, writeA);
    }
}

// Round 2
// 2872.300 us; speedup vs baseline: 1.1371x; 1.1371x over previous
//
#include <hip/hip_runtime.h>

#define LSZ 64
#define TILE 16

// Fused per-layer kernel, v2:
//  - weights/biases read from GLOBAL with wave-uniform indices -> compiler
//    emits s_load through the scalar/constant cache (dual-issues with VALU).
//    LDS holds only activations.
//  - h1/h2 stored [pos][ci] (ci contiguous, 64B per position) so conv reads
//    are 4x ds_read_b128 per tap; 2-way bank aliasing across lanes is free.
//  - In-place across layers is safe: conv input never reads B-site values
//    (masked to 0) and only B-sites are written.
__global__ __launch_bounds__(256, 3)
void discrete_flow_layer(const float* x_in,
                         float* x_out,
                         const float* __restrict__ W0,  // (3,3,1,16)
                         const float* __restrict__ B0,  // (16)
                         const float* __restrict__ W1,  // (3,3,16,16)
                         const float* __restrict__ B1,  // (16)
                         const float* __restrict__ W2,  // (3,3,16,1)
                         const float* __restrict__ B2,  // (1)
                         int parityA, int writeA)
{
    __shared__ float s_in[22 * 22];        // masked input tile (halo 3)
    __shared__ float s_h1[400 * 16];       // [pos(20x20)][ci]
    __shared__ float s_h2[324 * 16];       // [pos(18x18)][ci]

    const int tid  = threadIdx.x;
    const int tile = blockIdx.x;           // 0..15 (4x4 tiles of 16x16)
    const int b    = blockIdx.y;           // batch index
    const int r0 = (tile >> 2) * TILE;
    const int c0 = (tile & 3) * TILE;
    const float* xb = x_in + (size_t)b * (LSZ * LSZ);

    // ---- stage masked input tile (22x22, periodic wrap) ----
    for (int idx = tid; idx < 484; idx += 256) {
        int r = idx / 22, c = idx % 22;
        int gr = (r0 + r - 3) & 63;
        int gc = (c0 + c - 3) & 63;
        float v = xb[gr * 64 + gc];
        s_in[idx] = (((gr + gc) & 1) == parityA) ? v : 0.0f;
    }
    __syncthreads();

    // ---- conv1: 1 -> 16 over 20x20 ----
    for (int p = tid; p < 400; p += 256) {
        int ry = p / 20, rx = p % 20;
        float acc[16];
        #pragma unroll
        for (int c = 0; c < 16; ++c) acc[c] = B0[c];       // s_load (uniform)
        #pragma unroll
        for (int kh = 0; kh < 3; ++kh) {
            #pragma unroll
            for (int kw = 0; kw < 3; ++kw) {
                float v = s_in[(ry + kh) * 22 + rx + kw];
                const float* w = &W0[(kh * 3 + kw) * 16];  // uniform -> s_load
                #pragma unroll
                for (int c = 0; c < 16; ++c) acc[c] = fmaf(v, w[c], acc[c]);
            }
        }
        float* hp = &s_h1[p * 16];
        #pragma unroll
        for (int c = 0; c < 16; ++c) hp[c] = tanhf(acc[c]);
    }
    __syncthreads();

    // ---- conv2: 16 -> 16 over 18x18 (dominant cost) ----
    for (int p = tid; p < 324; p += 256) {
        int ry = p / 18, rx = p % 18;
        float acc[16];
        #pragma unroll
        for (int c = 0; c < 16; ++c) acc[c] = B1[c];       // uniform
        #pragma clang loop unroll(disable)
        for (int tap = 0; tap < 9; ++tap) {
            int kh = tap / 3, kw = tap % 3;
            const float* hv = &s_h1[((ry + kh) * 20 + rx + kw) * 16];
            float4 v0 = *(const float4*)&hv[0];
            float4 v1 = *(const float4*)&hv[4];
            float4 v2 = *(const float4*)&hv[8];
            float4 v3 = *(const float4*)&hv[12];
            float v[16] = {v0.x, v0.y, v0.z, v0.w, v1.x, v1.y, v1.z, v1.w,
                           v2.x, v2.y, v2.z, v2.w, v3.x, v3.y, v3.z, v3.w};
            const float* w = &W1[tap * 256];               // uniform -> s_load
            #pragma unroll
            for (int ci = 0; ci < 16; ++ci) {
                #pragma unroll
                for (int co = 0; co < 16; ++co)
                    acc[co] = fmaf(v[ci], w[ci * 16 + co], acc[co]);
            }
        }
        float* hp = &s_h2[p * 16];
        #pragma unroll
        for (int c = 0; c < 16; ++c) hp[c] = tanhf(acc[c]);
    }
    __syncthreads();

    // ---- conv3: 16 -> 1 over 16x16 + sign update ----
    {
        int p = tid;                       // exactly 256 positions
        int ry = p / 16, rx = p % 16;
        float acc = B2[0];
        #pragma clang loop unroll(disable)
        for (int tap = 0; tap < 9; ++tap) {
            int kh = tap / 3, kw = tap % 3;
            const float* hv = &s_h2[((ry + kh) * 18 + rx + kw) * 16];
            float4 v0 = *(const float4*)&hv[0];
            float4 v1 = *(const float4*)&hv[4];
            float4 v2 = *(const float4*)&hv[8];
            float4 v3 = *(const float4*)&hv[12];
            float v[16] = {v0.x, v0.y, v0.z, v0.w, v1.x, v1.y, v1.z, v1.w,
                           v2.x, v2.y, v2.z, v2.w, v3.x, v3.y, v3.z, v3.w};
            const float* w = &W2[tap * 16];                // uniform -> s_load
            #pragma unroll
            for (int ci = 0; ci < 16; ++ci)
                acc = fmaf(v[ci], w[ci], acc);
        }
        int gr = r0 + ry, gc = c0 + rx;
        size_t site = (size_t)b * (LSZ * LSZ) + gr * 64 + gc;
        bool isB = (((gr + gc) & 1) != parityA);
        float xv = x_in[site];
        if (isB) {
            float m = (acc > 0.0f) ? 1.0f : ((acc < 0.0f) ? -1.0f : 0.0f);
            x_out[site] = xv * m;
        } else if (writeA) {
            x_out[site] = xv;
        }
    }
}

extern "C" void kernel_launch(void* const* d_in, const int* in_sizes, int n_in,
                              void* d_out, int out_size, void* d_ws, size_t ws_size,
                              hipStream_t stream) {
    const float* z  = (const float*)d_in[0];
    const float* W0 = (const float*)d_in[1];
    const float* B0 = (const float*)d_in[2];
    const float* W1 = (const float*)d_in[3];
    const float* B1 = (const float*)d_in[4];
    const float* W2 = (const float*)d_in[5];
    const float* B2 = (const float*)d_in[6];
    float* out = (float*)d_out;

    dim3 grid(16, 1024);
    for (int layer = 0; layer < 4; ++layer) {
        const float* xin = (layer == 0) ? z : out;
        int writeA = (layer == 0) ? 1 : 0;
        int parityA = layer & 1;           // 'even' layers: A = even parity
        discrete_flow_layer<<<grid, 256, 0, stream>>>(
            xin, out,
            W0 + layer * 144, B0 + layer * 16,
            W1 + layer * 2304, B1 + layer * 16,
            W2 + layer * 144, B2 + layer * 1,
            parityA, writeA);
    }
}

// Round 3
// 1982.532 us; speedup vs baseline: 1.6475x; 1.4488x over previous
//
#include <hip/hip_runtime.h>

#define LSZ 64
#define TILE 16

// LDS plan (floats), 52,736 B total -> 3 blocks/CU:
//  [0    .. 5183]  s_h2 plane-major [ci][324]  (ALIASES s_in: 484 floats, dead after conv1)
//  [5184 .. 13183] s_h1 [pos(20x20)][stride 20] (padded: kills b128 bank conflicts)
#define H1_STRIDE 20
#define SMEM_FLOATS (5184 + 400 * H1_STRIDE)

__device__ __forceinline__ float fast_tanh(float x) {
    // tanh(x) = sign(x) * (1 - t) / (1 + t),  t = 2^(-2*log2(e)*|x|)
    float ax = __builtin_fabsf(x);
    float t  = __builtin_amdgcn_exp2f(ax * -2.885390081777927f);
    float r  = (1.0f - t) * __builtin_amdgcn_rcpf(1.0f + t);
    return __builtin_copysignf(r, x);
}

__global__ __launch_bounds__(256, 3)
void discrete_flow_layer(const float* x_in,
                         float* x_out,
                         const float* __restrict__ W0,  // (3,3,1,16)
                         const float* __restrict__ B0,  // (16)
                         const float* __restrict__ W1,  // (3,3,16,16)
                         const float* __restrict__ B1,  // (16)
                         const float* __restrict__ W2,  // (3,3,16,1)
                         const float* __restrict__ B2,  // (1)
                         int parityA, int writeA)
{
    __shared__ float smem[SMEM_FLOATS];
    float* s_in = smem;                    // 484 floats, dead after conv1
    float* s_h2 = smem;                    // [ci][324], live after conv2
    float* s_h1 = smem + 5184;             // [pos][H1_STRIDE]

    const int tid  = threadIdx.x;
    const int tile = blockIdx.x;           // 0..15 (4x4 tiles of 16x16)
    const int b    = blockIdx.y;           // batch index
    const int r0 = (tile >> 2) * TILE;
    const int c0 = (tile & 3) * TILE;
    const float* xb = x_in + (size_t)b * (LSZ * LSZ);

    // ---- stage masked input tile (22x22, periodic wrap) ----
    for (int idx = tid; idx < 484; idx += 256) {
        int r = idx / 22, c = idx % 22;
        int gr = (r0 + r - 3) & 63;
        int gc = (c0 + c - 3) & 63;
        float v = xb[gr * 64 + gc];
        s_in[idx] = (((gr + gc) & 1) == parityA) ? v : 0.0f;
    }
    __syncthreads();

    // ---- conv1: 1 -> 16 over 20x20 ----
    for (int p = tid; p < 400; p += 256) {
        int ry = p / 20, rx = p % 20;
        float acc[16];
        #pragma unroll
        for (int c = 0; c < 16; ++c) acc[c] = B0[c];       // uniform -> s_load
        #pragma unroll
        for (int kh = 0; kh < 3; ++kh) {
            #pragma unroll
            for (int kw = 0; kw < 3; ++kw) {
                float v = s_in[(ry + kh) * 22 + rx + kw];
                const float* w = &W0[(kh * 3 + kw) * 16];
                #pragma unroll
                for (int c = 0; c < 16; ++c) acc[c] = fmaf(v, w[c], acc[c]);
            }
        }
        float* hp = &s_h1[p * H1_STRIDE];
        #pragma unroll
        for (int c = 0; c < 16; ++c) hp[c] = fast_tanh(acc[c]);
    }
    __syncthreads();   // also: s_in reads done before s_h2 (alias) writes below

    // ---- conv2: 16 -> 16 over 18x18 (dominant cost) ----
    for (int p = tid; p < 324; p += 256) {
        int ry = p / 18, rx = p % 18;
        float acc[16];
        #pragma unroll
        for (int c = 0; c < 16; ++c) acc[c] = B1[c];       // uniform
        #pragma clang loop unroll(disable)
        for (int tap = 0; tap < 9; ++tap) {
            int kh = tap / 3, kw = tap % 3;
            const float* hv = &s_h1[((ry + kh) * 20 + rx + kw) * H1_STRIDE];
            float4 v0 = *(const float4*)&hv[0];
            float4 v1 = *(const float4*)&hv[4];
            float4 v2 = *(const float4*)&hv[8];
            float4 v3 = *(const float4*)&hv[12];
            float v[16] = {v0.x, v0.y, v0.z, v0.w, v1.x, v1.y, v1.z, v1.w,
                           v2.x, v2.y, v2.z, v2.w, v3.x, v3.y, v3.z, v3.w};
            const float* w = &W1[tap * 256];               // uniform -> s_load
            #pragma unroll
            for (int ci = 0; ci < 16; ++ci) {
                #pragma unroll
                for (int co = 0; co < 16; ++co)
                    acc[co] = fmaf(v[ci], w[ci * 16 + co], acc[co]);
            }
        }
        #pragma unroll
        for (int c = 0; c < 16; ++c)
            s_h2[c * 324 + p] = fast_tanh(acc[c]);         // plane-major, b32
    }
    __syncthreads();

    // ---- conv3: 16 -> 1 over 16x16 + sign update ----
    {
        int p = tid;                       // exactly 256 positions
        int ry = p / 16, rx = p % 16;
        float acc = B2[0];
        #pragma clang loop unroll(disable)
        for (int tap = 0; tap < 9; ++tap) {
            int kh = tap / 3, kw = tap % 3;
            int hp = (ry + kh) * 18 + rx + kw;
            const float* w = &W2[tap * 16];                // uniform -> s_load
            #pragma unroll
            for (int ci = 0; ci < 16; ++ci)
                acc = fmaf(s_h2[ci * 324 + hp], w[ci], acc);
        }
        int gr = r0 + ry, gc = c0 + rx;
        size_t site = (size_t)b * (LSZ * LSZ) + gr * 64 + gc;
        bool isB = (((gr + gc) & 1) != parityA);
        float xv = x_in[site];
        if (isB) {
            float m = (acc > 0.0f) ? 1.0f : ((acc < 0.0f) ? -1.0f : 0.0f);
            x_out[site] = xv * m;
        } else if (writeA) {
            x_out[site] = xv;
        }
    }
}

extern "C" void kernel_launch(void* const* d_in, const int* in_sizes, int n_in,
                              void* d_out, int out_size, void* d_ws, size_t ws_size,
                              hipStream_t stream) {
    const float* z  = (const float*)d_in[0];
    const float* W0 = (const float*)d_in[1];
    const float* B0 = (const float*)d_in[2];
    const float* W1 = (const float*)d_in[3];
    const float* B1 = (const float*)d_in[4];
    const float* W2 = (const float*)d_in[5];
    const float* B2 = (const float*)d_in[6];
    float* out = (float*)d_out;

    dim3 grid(16, 1024);
    for (int layer = 0; layer < 4; ++layer) {
        const float* xin = (layer == 0) ? z : out;
        int writeA = (layer == 0) ? 1 : 0;
        int parityA = layer & 1;           // 'even' layers: A = even parity
        discrete_flow_layer<<<grid, 256, 0, stream>>>(
            xin, out,
            W0 + layer * 144, B0 + layer * 16,
            W1 + layer * 2304, B1 + layer * 16,
            W2 + layer * 144, B2 + layer * 1,
            parityA, writeA);
    }
}

// Round 4
// 1530.066 us; speedup vs baseline: 2.1347x; 1.2957x over previous
//
#include <hip/hip_runtime.h>

#define LSZ 64
#define TILE 16

typedef _Float16 f16x8 __attribute__((ext_vector_type(8)));
typedef float    f32x4 __attribute__((ext_vector_type(4)));

// LDS plan (57,920 B total -> 2 blocks/CU):
//  s_h1: 400 pos x 40 f16 (80 B stride: [hi x16][lo x16][pad 8]) = 32,000 B
//  s_h2: 324 pos x 20 f32 (80 B stride: [f32 x16][pad 4])        = 25,920 B
//  s_in (484 f32) and s_B (w-fragments, 10,240 B) alias into s_h2 (dead until
//  conv2 epilogue; barrier-protected).

__device__ __forceinline__ float fast_tanh(float x) {
    float ax = __builtin_fabsf(x);
    float t  = __builtin_amdgcn_exp2f(ax * -2.885390081777927f);
    float r  = (1.0f - t) * __builtin_amdgcn_rcpf(1.0f + t);
    return __builtin_copysignf(r, x);
}

// split x (|x| < ~2) into f16 hi + f16 lo*2048 with subnormal-safe hi
__device__ __forceinline__ void split_f16(float x, _Float16& hi, _Float16& lo) {
    float h0 = (float)(_Float16)x;
    if (__builtin_fabsf(h0) < 6.104e-5f) h0 = 0.0f;   // avoid f16-subnormal hi
    hi = (_Float16)h0;
    lo = (_Float16)((x - h0) * 2048.0f);
}

__global__ __launch_bounds__(256, 2)
void discrete_flow_layer(const float* x_in,
                         float* x_out,
                         const float* __restrict__ w0g,  // (3,3,1,16)
                         const float* __restrict__ b0g,  // (16)
                         const float* __restrict__ w1g,  // (3,3,16,16) = [k=tap*16+ci][co]
                         const float* __restrict__ b1g,  // (16)
                         const float* __restrict__ w2g,  // (3,3,16,1)
                         const float* __restrict__ b2g,  // (1)
                         int parityA, int writeA)
{
    __shared__ __align__(16) _Float16 s_h1[400 * 40];
    __shared__ __align__(16) float    s_h2[324 * 20];
    float*    s_in = s_h2;                       // 484 floats, dead after conv1
    _Float16* s_B  = (_Float16*)(s_h2 + 512);    // 5120 f16, dead after reg-load

    const int tid  = threadIdx.x;
    const int tile = blockIdx.x;                 // 0..15 (4x4 tiles of 16x16)
    const int b    = blockIdx.y;
    const int r0 = (tile >> 2) * TILE;
    const int c0 = (tile & 3) * TILE;
    const float* xb = x_in + (size_t)b * (LSZ * LSZ);

    // ---- phase 0: stage masked input tile + build weight fragments ----
    for (int idx = tid; idx < 484; idx += 256) {
        int r = idx / 22, c = idx % 22;
        int gr = (r0 + r - 3) & 63;
        int gc = (c0 + c - 3) & 63;
        float v = xb[gr * 64 + gc];
        s_in[idx] = (((gr + gc) & 1) == parityA) ? v : 0.0f;
    }
    // B-fragment layout assumption (16x16x32): lane holds B[k][n] with
    // n = lane&15, k = (lane>>4)*8 + j.  k = tap*16 + ci, padded 144->160.
    for (int e = tid; e < 320; e += 256) {
        int c = e >> 6, lane = e & 63;
        int q = lane >> 4, co = lane & 15;
        #pragma unroll
        for (int j = 0; j < 8; ++j) {
            int k = c * 32 + q * 8 + j;
            float w = (k < 144) ? w1g[k * 16 + co] : 0.0f;
            _Float16 whi, wlo;
            split_f16(w, whi, wlo);
            s_B[((c * 2 + 0) * 64 + lane) * 8 + j] = whi;
            s_B[((c * 2 + 1) * 64 + lane) * 8 + j] = wlo;
        }
    }
    __syncthreads();

    // ---- phase 1: conv1 (fp32 VALU) + tanh + split-f16 store ----
    for (int p = tid; p < 400; p += 256) {
        int ry = p / 20, rx = p % 20;
        float acc[16];
        #pragma unroll
        for (int c = 0; c < 16; ++c) acc[c] = b0g[c];
        #pragma unroll
        for (int kh = 0; kh < 3; ++kh) {
            #pragma unroll
            for (int kw = 0; kw < 3; ++kw) {
                float v = s_in[(ry + kh) * 22 + rx + kw];
                const float* w = &w0g[(kh * 3 + kw) * 16];
                #pragma unroll
                for (int c = 0; c < 16; ++c) acc[c] = fmaf(v, w[c], acc[c]);
            }
        }
        f16x8 vh0, vh1, vl0, vl1;
        #pragma unroll
        for (int c = 0; c < 8; ++c) {
            _Float16 hi, lo;
            split_f16(fast_tanh(acc[c]), hi, lo);
            vh0[c] = hi; vl0[c] = lo;
        }
        #pragma unroll
        for (int c = 0; c < 8; ++c) {
            _Float16 hi, lo;
            split_f16(fast_tanh(acc[8 + c]), hi, lo);
            vh1[c] = hi; vl1[c] = lo;
        }
        _Float16* hp = &s_h1[p * 40];
        *(f16x8*)&hp[0]  = vh0;
        *(f16x8*)&hp[8]  = vh1;
        *(f16x8*)&hp[16] = vl0;
        *(f16x8*)&hp[24] = vl1;
    }
    __syncthreads();

    // ---- phase 2: load weight fragments + bias to registers ----
    const int lane = tid & 63;
    const int wv   = tid >> 6;
    f16x8 Bh[5], Bl[5];
    #pragma unroll
    for (int c = 0; c < 5; ++c) {
        Bh[c] = *(const f16x8*)&s_B[((c * 2 + 0) * 64 + lane) * 8];
        Bl[c] = *(const f16x8*)&s_B[((c * 2 + 1) * 64 + lane) * 8];
    }
    const float b1v = b1g[lane & 15];
    __syncthreads();   // s_B / s_in region must be fully read before h2 writes

    // ---- phase 3: conv2 = implicit GEMM via MFMA (M=324 pad 336, N=16, K=144 pad 160) ----
    {
        const int m0 = lane & 15, q = lane >> 4;
        const int qh = q >> 1, ql = q & 1;
        // A-layout assumption: lane holds A[m][k], m = lane&15, k = (lane>>4)*8 + j.
        // q selects (tap-parity, ci-half): q=0:(2c,ci0-7) q=1:(2c,ci8-15) q=2:(2c+1,ci0-7) q=3:(2c+1,ci8-15)
        // TAPOFF[t] = ((t/3)*20 + t%3)*40 f16 units; tap 9 clamped (B is zero there)
        const int T0 = 0, T1 = 40, T2 = 80, T3 = 800, T4 = 840,
                  T5 = 880, T6 = 1600, T7 = 1640, T8 = 1680, T9 = 1680;
        for (int mt = wv; mt < 21; mt += 4) {
            int m_abs = mt * 16 + m0;
            if (m_abs > 323) m_abs = 323;          // clamp: rows >=324 discarded
            int oy = m_abs / 18, ox = m_abs % 18;
            int abase = (oy * 20 + ox) * 40 + ql * 8;
            f32x4 C0 = {0.f, 0.f, 0.f, 0.f};
            f32x4 C1 = {0.f, 0.f, 0.f, 0.f};
            int off;
            f16x8 A0, A1;
            #define CONV2_STEP(cc, TA, TB)                                        \
                off = qh ? (TB) : (TA);                                           \
                A0 = *(const f16x8*)&s_h1[abase + off];                           \
                A1 = *(const f16x8*)&s_h1[abase + off + 16];                      \
                C0 = __builtin_amdgcn_mfma_f32_16x16x32_f16(A0, Bh[cc], C0, 0, 0, 0); \
                C1 = __builtin_amdgcn_mfma_f32_16x16x32_f16(A0, Bl[cc], C1, 0, 0, 0); \
                C1 = __builtin_amdgcn_mfma_f32_16x16x32_f16(A1, Bh[cc], C1, 0, 0, 0);
            CONV2_STEP(0, T0, T1)
            CONV2_STEP(1, T2, T3)
            CONV2_STEP(2, T4, T5)
            CONV2_STEP(3, T6, T7)
            CONV2_STEP(4, T8, T9)
            #undef CONV2_STEP
            // D layout (verified): col = lane&15 (= co), row = q*4 + r (= m)
            #pragma unroll
            for (int r = 0; r < 4; ++r) {
                int m_out = mt * 16 + q * 4 + r;
                if (m_out < 324) {
                    float val = C0[r] + C1[r] * (1.0f / 2048.0f) + b1v;
                    s_h2[m_out * 20 + m0] = fast_tanh(val);
                }
            }
        }
    }
    __syncthreads();

    // ---- phase 4: conv3 (fp32 VALU, b128 LDS reads) + sign update ----
    {
        int p = tid;                       // exactly 256 positions
        int ry = p / 16, rx = p % 16;
        float acc = b2g[0];
        #pragma clang loop unroll(disable)
        for (int tap = 0; tap < 9; ++tap) {
            int kh = tap / 3, kw = tap % 3;
            const float* hv = &s_h2[((ry + kh) * 18 + rx + kw) * 20];
            float4 v0 = *(const float4*)&hv[0];
            float4 v1 = *(const float4*)&hv[4];
            float4 v2 = *(const float4*)&hv[8];
            float4 v3 = *(const float4*)&hv[12];
            float v[16] = {v0.x, v0.y, v0.z, v0.w, v1.x, v1.y, v1.z, v1.w,
                           v2.x, v2.y, v2.z, v2.w, v3.x, v3.y, v3.z, v3.w};
            const float* w = &w2g[tap * 16];
            #pragma unroll
            for (int ci = 0; ci < 16; ++ci)
                acc = fmaf(v[ci], w[ci], acc);
        }
        int gr = r0 + ry, gc = c0 + rx;
        size_t site = (size_t)b * (LSZ * LSZ) + gr * 64 + gc;
        bool isB = (((gr + gc) & 1) != parityA);
        float xv = x_in[site];
        if (isB) {
            float m = (acc > 0.0f) ? 1.0f : ((acc < 0.0f) ? -1.0f : 0.0f);
            x_out[site] = xv * m;
        } else if (writeA) {
            x_out[site] = xv;
        }
    }
}

extern "C" void kernel_launch(void* const* d_in, const int* in_sizes, int n_in,
                              void* d_out, int out_size, void* d_ws, size_t ws_size,
                              hipStream_t stream) {
    const float* z  = (const float*)d_in[0];
    const float* W0 = (const float*)d_in[1];
    const float* B0 = (const float*)d_in[2];
    const float* W1 = (const float*)d_in[3];
    const float* B1 = (const float*)d_in[4];
    const float* W2 = (const float*)d_in[5];
    const float* B2 = (const float*)d_in[6];
    float* out = (float*)d_out;

    dim3 grid(16, 1024);
    for (int layer = 0; layer < 4; ++layer) {
        const float* xin = (layer == 0) ? z : out;
        int writeA = (layer == 0) ? 1 : 0;
        int parityA = layer & 1;
        discrete_flow_layer<<<grid, 256, 0, stream>>>(
            xin, out,
            W0 + layer * 144, B0 + layer * 16,
            W1 + layer * 2304, B1 + layer * 16,
            W2 + layer * 144, B2 + layer * 1,
            parityA, writeA);
    }
}

// Round 6
// 818.712 us; speedup vs baseline: 3.9894x; 1.8689x over previous
//
#include <hip/hip_runtime.h>

#define LSZ 64
#define TILE 16

typedef _Float16 f16x8 __attribute__((ext_vector_type(8)));
typedef float    f32x4 __attribute__((ext_vector_type(4)));

// LDS plan (52,800 B -> 3 blocks/CU):
//  s_h1: 400 pos x 40 f16 (80B stride: [hi x16][lo x16][pad 8]) = 32,000 B
//  s_h2: plane-major f32 [ci][325]                               = 20,800 B
//  s_in (484 f32) aliases s_h2 (dead until conv2 epilogue; barrier-protected)

__device__ __forceinline__ float fast_tanh(float x) {
    float ax = __builtin_fabsf(x);
    float t  = __builtin_amdgcn_exp2f(ax * -2.885390081777927f);
    float r  = (1.0f - t) * __builtin_amdgcn_rcpf(1.0f + t);
    return __builtin_copysignf(r, x);
}

// split x into f16 hi + f16 lo*2048; hi flushed if f16-subnormal (MFMA-safe)
__device__ __forceinline__ void split_f16(float x, _Float16& hi, _Float16& lo) {
    float h0 = (float)(_Float16)x;
    if (__builtin_fabsf(h0) < 6.104e-5f) h0 = 0.0f;
    hi = (_Float16)h0;
    lo = (_Float16)((x - h0) * 2048.0f);
}

// Precompute conv2 weight MFMA fragments (split-f16) once into d_ws.
// Layout: ws[layer*5120 + ((c*2+h)*64 + lane)*8 + j], c=K-chunk 0..4, h=hi/lo.
__global__ void build_wfrags(const float* __restrict__ W1, _Float16* __restrict__ ws) {
    int layer = blockIdx.x, tid = threadIdx.x;
    const float* w1g = W1 + layer * 2304;
    _Float16* o = ws + layer * 5120;
    for (int e = tid; e < 320; e += 256) {
        int c = e >> 6, lane = e & 63;
        int q = lane >> 4, co = lane & 15;
        #pragma unroll
        for (int j = 0; j < 8; ++j) {
            int k = c * 32 + q * 8 + j;           // k = tap*16 + ci, padded 144->160
            float w = (k < 144) ? w1g[k * 16 + co] : 0.0f;
            _Float16 whi, wlo;
            split_f16(w, whi, wlo);
            o[((c * 2 + 0) * 64 + lane) * 8 + j] = whi;
            o[((c * 2 + 1) * 64 + lane) * 8 + j] = wlo;
        }
    }
}

__global__ __launch_bounds__(256, 3)
void discrete_flow_layer(const float* x_in,
                         float* x_out,
                         const float* __restrict__ w0g,  // (3,3,1,16)
                         const float* __restrict__ b0g,  // (16)
                         const _Float16* __restrict__ wfr, // prebuilt fragments
                         const float* __restrict__ b1g,  // (16)
                         const float* __restrict__ w2g,  // (3,3,16,1)
                         const float* __restrict__ b2g,  // (1)
                         int parityA, int writeA)
{
    __shared__ __align__(16) _Float16 s_h1[400 * 40];
    __shared__ __align__(16) float    s_h2[16 * 325];   // plane-major [ci][pos]
    float* s_in = s_h2;                                  // 484 f32, dead after conv1

    const int tid  = threadIdx.x;
    const int lane = tid & 63;
    const int wv   = tid >> 6;
    const int tile = blockIdx.x;
    const int b    = blockIdx.y;
    const int r0 = (tile >> 2) * TILE;
    const int c0 = (tile & 3) * TILE;
    const float* xb = x_in + (size_t)b * (LSZ * LSZ);

    // ---- prefetch weight fragments + bias (global, L2-hot) ----
    f16x8 Bh[5], Bl[5];
    #pragma unroll
    for (int c = 0; c < 5; ++c) {
        Bh[c] = *(const f16x8*)&wfr[((c * 2 + 0) * 64 + lane) * 8];
        Bl[c] = *(const f16x8*)&wfr[((c * 2 + 1) * 64 + lane) * 8];
    }
    const float b1v = b1g[lane & 15];

    // ---- phase 0: stage masked input tile (22x22, wrap) ----
    for (int idx = tid; idx < 484; idx += 256) {
        int r = idx / 22, c = idx % 22;
        int gr = (r0 + r - 3) & 63;
        int gc = (c0 + c - 3) & 63;
        float v = xb[gr * 64 + gc];
        s_in[idx] = (((gr + gc) & 1) == parityA) ? v : 0.0f;
    }
    __syncthreads();

    // ---- phase 1: conv1 (parity-split: half the taps are exactly zero) ----
    // pp<200: positions with (ry+rx) even; else odd. Wave-mostly-uniform.
    for (int pp = tid; pp < 400; pp += 256) {
        int g  = (pp >= 200);
        int pi = pp - g * 200;
        int ry = pi / 10;
        int rx = 2 * (pi % 10) + ((ry ^ g) & 1);
        int base = ry * 22 + rx;
        float acc[16];
        #pragma unroll
        for (int c = 0; c < 16; ++c) acc[c] = b0g[c];
        if ((g ^ parityA) == 0) {          // 5 even-sum taps: (0,0)(0,2)(1,1)(2,0)(2,2)
            const int off[5] = {0, 2, 23, 44, 46};
            const int wt[5]  = {0, 2, 4, 6, 8};
            #pragma unroll
            for (int t = 0; t < 5; ++t) {
                float v = s_in[base + off[t]];
                const float* w = &w0g[wt[t] * 16];
                #pragma unroll
                for (int c = 0; c < 16; ++c) acc[c] = fmaf(v, w[c], acc[c]);
            }
        } else {                            // 4 odd-sum taps: (0,1)(1,0)(1,2)(2,1)
            const int off[4] = {1, 22, 24, 45};   // (2,1) = 2*22+1 = 45 (R5 bug: was 43)
            const int wt[4]  = {1, 3, 5, 7};
            #pragma unroll
            for (int t = 0; t < 4; ++t) {
                float v = s_in[base + off[t]];
                const float* w = &w0g[wt[t] * 16];
                #pragma unroll
                for (int c = 0; c < 16; ++c) acc[c] = fmaf(v, w[c], acc[c]);
            }
        }
        int p = ry * 20 + rx;
        f16x8 vh0, vh1, vl0, vl1;
        #pragma unroll
        for (int c = 0; c < 8; ++c) {
            _Float16 hi, lo;
            split_f16(fast_tanh(acc[c]), hi, lo);
            vh0[c] = hi; vl0[c] = lo;
        }
        #pragma unroll
        for (int c = 0; c < 8; ++c) {
            _Float16 hi, lo;
            split_f16(fast_tanh(acc[8 + c]), hi, lo);
            vh1[c] = hi; vl1[c] = lo;
        }
        _Float16* hp = &s_h1[p * 40];
        *(f16x8*)&hp[0]  = vh0;
        *(f16x8*)&hp[8]  = vh1;
        *(f16x8*)&hp[16] = vl0;
        *(f16x8*)&hp[24] = vl1;
    }
    __syncthreads();   // h1 ready; s_in reads done before s_h2 (alias) writes

    // ---- phase 3: conv2 = MFMA implicit GEMM (M=324, N=16, K=144->160) ----
    {
        const int m0 = lane & 15, q = lane >> 4;
        const int qh = q >> 1, ql = q & 1;
        const int T0 = 0, T1 = 40, T2 = 80, T3 = 800, T4 = 840,
                  T5 = 880, T6 = 1600, T7 = 1640, T8 = 1680, T9 = 1680;
        for (int mt = wv; mt < 21; mt += 4) {
            int m_abs = mt * 16 + m0;
            if (m_abs > 323) m_abs = 323;
            int oy = m_abs / 18, ox = m_abs % 18;
            int abase = (oy * 20 + ox) * 40 + ql * 8;
            f32x4 C0 = {0.f, 0.f, 0.f, 0.f};
            f32x4 C1 = {0.f, 0.f, 0.f, 0.f};
            int off;
            f16x8 A0, A1;
            #define CONV2_STEP(cc, TA, TB)                                        \
                off = qh ? (TB) : (TA);                                           \
                A0 = *(const f16x8*)&s_h1[abase + off];                           \
                A1 = *(const f16x8*)&s_h1[abase + off + 16];                      \
                C0 = __builtin_amdgcn_mfma_f32_16x16x32_f16(A0, Bh[cc], C0, 0, 0, 0); \
                C1 = __builtin_amdgcn_mfma_f32_16x16x32_f16(A0, Bl[cc], C1, 0, 0, 0); \
                C1 = __builtin_amdgcn_mfma_f32_16x16x32_f16(A1, Bh[cc], C1, 0, 0, 0);
            CONV2_STEP(0, T0, T1)
            CONV2_STEP(1, T2, T3)
            CONV2_STEP(2, T4, T5)
            CONV2_STEP(3, T6, T7)
            CONV2_STEP(4, T8, T9)
            #undef CONV2_STEP
            // D layout: col(lane&15)=co, row=q*4+r = m.  Plane-major store.
            #pragma unroll
            for (int r = 0; r < 4; ++r) {
                int m_out = mt * 16 + q * 4 + r;
                if (m_out < 324) {
                    float val = C0[r] + C1[r] * (1.0f / 2048.0f) + b1v;
                    s_h2[m0 * 325 + m_out] = fast_tanh(val);
                }
            }
        }
    }
    __syncthreads();

    // ---- phase 4: conv3 (fp32 VALU, conflict-free b32 + immediate offsets) ----
    {
        int p = tid;
        int ry = p >> 4, rx = p & 15;
        float acc = b2g[0];
        #pragma unroll
        for (int tap = 0; tap < 9; ++tap) {
            int kh = tap / 3, kw = tap % 3;
            int hp = (ry + kh) * 18 + rx + kw;
            const float* w = &w2g[tap * 16];
            #pragma unroll
            for (int ci = 0; ci < 16; ++ci)
                acc = fmaf(s_h2[ci * 325 + hp], w[ci], acc);
        }
        int gr = r0 + ry, gc = c0 + rx;
        size_t site = (size_t)b * (LSZ * LSZ) + gr * 64 + gc;
        bool isB = (((gr + gc) & 1) != parityA);
        float xv = x_in[site];
        if (isB) {
            float m = (acc > 0.0f) ? 1.0f : ((acc < 0.0f) ? -1.0f : 0.0f);
            x_out[site] = xv * m;
        } else if (writeA) {
            x_out[site] = xv;
        }
    }
}

extern "C" void kernel_launch(void* const* d_in, const int* in_sizes, int n_in,
                              void* d_out, int out_size, void* d_ws, size_t ws_size,
                              hipStream_t stream) {
    const float* z  = (const float*)d_in[0];
    const float* W0 = (const float*)d_in[1];
    const float* B0 = (const float*)d_in[2];
    const float* W1 = (const float*)d_in[3];
    const float* B1 = (const float*)d_in[4];
    const float* W2 = (const float*)d_in[5];
    const float* B2 = (const float*)d_in[6];
    float* out = (float*)d_out;
    _Float16* wfr = (_Float16*)d_ws;      // 4 * 5120 f16 = 40,960 B

    build_wfrags<<<dim3(4), 256, 0, stream>>>(W1, wfr);

    dim3 grid(16, 1024);
    for (int layer = 0; layer < 4; ++layer) {
        const float* xin = (layer == 0) ? z : out;
        int writeA = (layer == 0) ? 1 : 0;
        int parityA = layer & 1;
        discrete_flow_layer<<<grid, 256, 0, stream>>>(
            xin, out,
            W0 + layer * 144, B0 + layer * 16,
            wfr + layer * 5120, B1 + layer * 16,
            W2 + layer * 144, B2 + layer * 1,
            parityA, writeA);
    }
}

// Round 8
// 724.146 us; speedup vs baseline: 4.5104x; 1.1306x over previous
//
#include <hip/hip_runtime.h>

#define LSZ 64
#define TILE 16

typedef _Float16 f16x8 __attribute__((ext_vector_type(8)));
typedef float    f32x4 __attribute__((ext_vector_type(4)));

// LDS plan (52,800 B -> 3 blocks/CU):  [identical to R6]
//  s_h1: 400 pos x 40 f16 ([hi x16][lo x16][pad 8]) = 32,000 B
//  s_h2: plane-major f32 [ci][325]                  = 20,800 B
//  s_in (484 f32) aliases s_h2 (dead until conv2 store; barrier-protected)
//
// d_ws (f16 units): [0)      conv2 frags 4 x 5120
//                   [20480)  h1 tables   4 x 1536  (48 entries x [hi16][lo16])
// total 53,248 B.
//
// BISECTION NOTE (R8): table entries are built with fmaf(+-1,w,acc) chains in
// R6's exact tap order + fast_tanh + split_f16 -> table h1 is BIT-IDENTICAL
// to R6's computed h1. Tail (conv2/conv3/sign) is R6's verbatim passing code.
// Any failure here isolates the table LOOKUP indexing.

__device__ __forceinline__ float fast_tanh(float x) {
    float ax = __builtin_fabsf(x);
    float t  = __builtin_amdgcn_exp2f(ax * -2.885390081777927f);
    float r  = (1.0f - t) * __builtin_amdgcn_rcpf(1.0f + t);
    return __builtin_copysignf(r, x);
}

// split x into f16 hi + f16 lo*2048; hi flushed if f16-subnormal (MFMA-safe)
__device__ __forceinline__ void split_f16(float x, _Float16& hi, _Float16& lo) {
    float h0 = (float)(_Float16)x;
    if (__builtin_fabsf(h0) < 6.104e-5f) h0 = 0.0f;
    hi = (_Float16)h0;
    lo = (_Float16)((x - h0) * 2048.0f);
}

__global__ void prep(const float* __restrict__ W0, const float* __restrict__ B0,
                     const float* __restrict__ W1, _Float16* __restrict__ ws) {
    const int layer = blockIdx.x, tid = threadIdx.x;
    // ---- conv2 weight fragments (k = tap*16+ci, padded 144->160) ----
    const float* w1g = W1 + layer * 2304;
    _Float16* o2 = ws + layer * 5120;
    for (int e = tid; e < 320; e += 256) {
        int c = e >> 6, lane = e & 63;
        int q = lane >> 4, co = lane & 15;
        #pragma unroll
        for (int j = 0; j < 8; ++j) {
            int k = c * 32 + q * 8 + j;
            float w = (k < 144) ? w1g[k * 16 + co] : 0.0f;
            _Float16 whi, wlo;
            split_f16(w, whi, wlo);
            o2[((c * 2 + 0) * 64 + lane) * 8 + j] = whi;
            o2[((c * 2 + 1) * 64 + lane) * 8 + j] = wlo;
        }
    }
    // ---- h1 tables: 32 even-parity + 16 odd-parity patterns ----
    // BIT-IDENTICAL to R6's conv1: fmaf(+-1, w, acc) chain, same tap order,
    // then fast_tanh + split_f16.
    const float* w0g = W0 + layer * 144;
    const float* b0g = B0 + layer * 16;
    _Float16* ot = ws + 20480 + layer * 1536;
    for (int e = tid; e < 48; e += 256) {
        int sel = (e >= 32);
        int bits = sel ? (e - 32) : e;
        const int wtE[5] = {0, 2, 4, 6, 8};   // taps (0,0)(0,2)(1,1)(2,0)(2,2)
        const int wtO[4] = {1, 3, 5, 7};      // taps (0,1)(1,0)(1,2)(2,1)
        for (int ch = 0; ch < 16; ++ch) {
            float u = b0g[ch];
            if (!sel) {
                #pragma unroll
                for (int t = 0; t < 5; ++t) {
                    float s = ((bits >> t) & 1) ? 1.0f : -1.0f;
                    u = fmaf(s, w0g[wtE[t] * 16 + ch], u);
                }
            } else {
                #pragma unroll
                for (int t = 0; t < 4; ++t) {
                    float s = ((bits >> t) & 1) ? 1.0f : -1.0f;
                    u = fmaf(s, w0g[wtO[t] * 16 + ch], u);
                }
            }
            _Float16 hi, lo;
            split_f16(fast_tanh(u), hi, lo);
            ot[e * 32 + ch]      = hi;
            ot[e * 32 + 16 + ch] = lo;
        }
    }
}

__global__ __launch_bounds__(256, 3)
void discrete_flow_layer(const float* x_in,
                         float* x_out,
                         const _Float16* __restrict__ wfr,  // conv2 fragments
                         const _Float16* __restrict__ tbl,  // h1 table
                         const float* __restrict__ b1g,     // (16)
                         const float* __restrict__ w2g,     // (3,3,16,1)
                         const float* __restrict__ b2g,     // (1)
                         int parityA, int writeA)
{
    __shared__ __align__(16) _Float16 s_h1[400 * 40];
    __shared__ __align__(16) float    s_h2[16 * 325];   // plane-major [ci][pos]
    float* s_in = s_h2;                                  // 484 f32, dead after phase 1

    const int tid  = threadIdx.x;
    const int lane = tid & 63;
    const int wv   = tid >> 6;
    const int tile = blockIdx.x;
    const int b    = blockIdx.y;
    const int r0 = (tile >> 2) * TILE;
    const int c0 = (tile & 3) * TILE;
    const float* xb = x_in + (size_t)b * (LSZ * LSZ);

    // ---- prefetch conv2 weight fragments + bias (global, L2-hot) ----
    f16x8 Bh[5], Bl[5];
    #pragma unroll
    for (int c = 0; c < 5; ++c) {
        Bh[c] = *(const f16x8*)&wfr[((c * 2 + 0) * 64 + lane) * 8];
        Bl[c] = *(const f16x8*)&wfr[((c * 2 + 1) * 64 + lane) * 8];
    }
    const float b1v = b1g[lane & 15];

    // ---- phase 0: stage masked input tile (22x22, wrap) ----
    for (int idx = tid; idx < 484; idx += 256) {
        int r = idx / 22, c = idx % 22;
        int gr = (r0 + r - 3) & 63;
        int gc = (c0 + c - 3) & 63;
        float v = xb[gr * 64 + gc];
        s_in[idx] = (((gr + gc) & 1) == parityA) ? v : 0.0f;
    }
    __syncthreads();

    // ---- phase 1: h1 by pattern-table lookup ----
    for (int pp = tid; pp < 400; pp += 256) {
        int g  = (pp >= 200);
        int pi = pp - g * 200;
        int ry = pi / 10;
        int rx = 2 * (pi % 10) + ((ry ^ g) & 1);
        int base = ry * 22 + rx;
        int sel = g ^ parityA;
        int idx = 0;
        if (sel == 0) {                        // even-sum taps, 32 patterns
            const int off[5] = {0, 2, 23, 44, 46};
            #pragma unroll
            for (int t = 0; t < 5; ++t)
                idx |= (s_in[base + off[t]] > 0.0f) << t;
        } else {                               // odd-sum taps, 16 patterns
            const int off[4] = {1, 22, 24, 45};
            #pragma unroll
            for (int t = 0; t < 4; ++t)
                idx |= (s_in[base + off[t]] > 0.0f) << t;
        }
        const f16x8* row = (const f16x8*)&tbl[(sel ? 1024 : 0) + idx * 32];
        f16x8* hp = (f16x8*)&s_h1[(ry * 20 + rx) * 40];
        hp[0] = row[0]; hp[1] = row[1]; hp[2] = row[2]; hp[3] = row[3];
    }
    __syncthreads();   // h1 ready; s_in reads done before s_h2 (alias) writes

    // ---- phase 2: conv2 MFMA (M=324, N=16, K=144->160)  [R6 verbatim] ----
    {
        const int m0 = lane & 15, q = lane >> 4;
        const int qh = q >> 1, ql = q & 1;
        const int T0 = 0, T1 = 40, T2 = 80, T3 = 800, T4 = 840,
                  T5 = 880, T6 = 1600, T7 = 1640, T8 = 1680, T9 = 1680;
        for (int mt = wv; mt < 21; mt += 4) {
            int m_abs = mt * 16 + m0;
            if (m_abs > 323) m_abs = 323;
            int oy = m_abs / 18, ox = m_abs % 18;
            int abase = (oy * 20 + ox) * 40 + ql * 8;
            f32x4 C0 = {0.f, 0.f, 0.f, 0.f};
            f32x4 C1 = {0.f, 0.f, 0.f, 0.f};
            int off;
            f16x8 A0, A1;
            #define CONV2_STEP(cc, TA, TB)                                        \
                off = qh ? (TB) : (TA);                                           \
                A0 = *(const f16x8*)&s_h1[abase + off];                           \
                A1 = *(const f16x8*)&s_h1[abase + off + 16];                      \
                C0 = __builtin_amdgcn_mfma_f32_16x16x32_f16(A0, Bh[cc], C0, 0, 0, 0); \
                C1 = __builtin_amdgcn_mfma_f32_16x16x32_f16(A0, Bl[cc], C1, 0, 0, 0); \
                C1 = __builtin_amdgcn_mfma_f32_16x16x32_f16(A1, Bh[cc], C1, 0, 0, 0);
            CONV2_STEP(0, T0, T1)
            CONV2_STEP(1, T2, T3)
            CONV2_STEP(2, T4, T5)
            CONV2_STEP(3, T6, T7)
            CONV2_STEP(4, T8, T9)
            #undef CONV2_STEP
            // D layout: col(lane&15)=co, row=q*4+r = m.  Plane-major store.
            #pragma unroll
            for (int r = 0; r < 4; ++r) {
                int m_out = mt * 16 + q * 4 + r;
                if (m_out < 324) {
                    float val = C0[r] + C1[r] * (1.0f / 2048.0f) + b1v;
                    s_h2[m0 * 325 + m_out] = fast_tanh(val);
                }
            }
        }
    }
    __syncthreads();

    // ---- phase 3: conv3 (fp32 VALU) + sign update  [R6 verbatim] ----
    {
        int p = tid;
        int ry = p >> 4, rx = p & 15;
        float acc = b2g[0];
        #pragma unroll
        for (int tap = 0; tap < 9; ++tap) {
            int kh = tap / 3, kw = tap % 3;
            int hp = (ry + kh) * 18 + rx + kw;
            const float* w = &w2g[tap * 16];
            #pragma unroll
            for (int ci = 0; ci < 16; ++ci)
                acc = fmaf(s_h2[ci * 325 + hp], w[ci], acc);
        }
        int gr = r0 + ry, gc = c0 + rx;
        size_t site = (size_t)b * (LSZ * LSZ) + gr * 64 + gc;
        bool isB = (((gr + gc) & 1) != parityA);
        float xv = x_in[site];
        if (isB) {
            float m = (acc > 0.0f) ? 1.0f : ((acc < 0.0f) ? -1.0f : 0.0f);
            x_out[site] = xv * m;
        } else if (writeA) {
            x_out[site] = xv;
        }
    }
}

extern "C" void kernel_launch(void* const* d_in, const int* in_sizes, int n_in,
                              void* d_out, int out_size, void* d_ws, size_t ws_size,
                              hipStream_t stream) {
    const float* z  = (const float*)d_in[0];
    const float* W0 = (const float*)d_in[1];
    const float* B0 = (const float*)d_in[2];
    const float* W1 = (const float*)d_in[3];
    const float* B1 = (const float*)d_in[4];
    const float* W2 = (const float*)d_in[5];
    const float* B2 = (const float*)d_in[6];
    float* out = (float*)d_out;
    _Float16* ws = (_Float16*)d_ws;   // 53,248 B used

    prep<<<dim3(4), 256, 0, stream>>>(W0, B0, W1, ws);

    dim3 grid(16, 1024);
    for (int layer = 0; layer < 4; ++layer) {
        const float* xin = (layer == 0) ? z : out;
        int writeA = (layer == 0) ? 1 : 0;
        int parityA = layer & 1;
        discrete_flow_layer<<<grid, 256, 0, stream>>>(
            xin, out,
            ws + layer * 5120,
            ws + 20480 + layer * 1536,
            B1 + layer * 16,
            W2 + layer * 144,
            B2 + layer * 1,
            parityA, writeA);
    }
}

// Round 9
// 640.686 us; speedup vs baseline: 5.0980x; 1.1303x over previous
//
#include <hip/hip_runtime.h>

#define LSZ 64
#define TILE 16

typedef _Float16 f16x8 __attribute__((ext_vector_type(8)));
typedef float    f32x4 __attribute__((ext_vector_type(4)));

// LDS plan (33,936 B -> 4 blocks/CU):
//  s_h1: 400 pos x 40 f16 ([hi x16][lo x16][pad 8]) = 32,000 B
//        ALIASED by s_h2 (f32 plane-major [ci][325] = 20,800 B) after conv2;
//        conv2 D staged in registers across the barrier (scheduling only —
//        h2 VALUES are bit-identical to R8's passing kernel).
//  s_in: 484 f32 = 1,936 B (separate; live through phase 1 only)
//
// d_ws (f16 units): [0)      conv2 frags 4 x 5120
//                   [20480)  h1 tables   4 x 1536  (48 entries x [hi16][lo16])
//
// NUMERICS RULE (R7 post-mortem): sign-decision margin is ~1e-6. Everything
// feeding the logit (table entries, conv2 split-MFMA, h2 f32 values, conv3
// fp32 chain) must stay bit-identical to the R8-proven pipeline.

__device__ __forceinline__ float fast_tanh(float x) {
    float ax = __builtin_fabsf(x);
    float t  = __builtin_amdgcn_exp2f(ax * -2.885390081777927f);
    float r  = (1.0f - t) * __builtin_amdgcn_rcpf(1.0f + t);
    return __builtin_copysignf(r, x);
}

// split x into f16 hi + f16 lo*2048; hi flushed if f16-subnormal (MFMA-safe)
__device__ __forceinline__ void split_f16(float x, _Float16& hi, _Float16& lo) {
    float h0 = (float)(_Float16)x;
    if (__builtin_fabsf(h0) < 6.104e-5f) h0 = 0.0f;
    hi = (_Float16)h0;
    lo = (_Float16)((x - h0) * 2048.0f);
}

__global__ void prep(const float* __restrict__ W0, const float* __restrict__ B0,
                     const float* __restrict__ W1, _Float16* __restrict__ ws) {
    const int layer = blockIdx.x, tid = threadIdx.x;
    // ---- conv2 weight fragments (k = tap*16+ci, padded 144->160) ----
    const float* w1g = W1 + layer * 2304;
    _Float16* o2 = ws + layer * 5120;
    for (int e = tid; e < 320; e += 256) {
        int c = e >> 6, lane = e & 63;
        int q = lane >> 4, co = lane & 15;
        #pragma unroll
        for (int j = 0; j < 8; ++j) {
            int k = c * 32 + q * 8 + j;
            float w = (k < 144) ? w1g[k * 16 + co] : 0.0f;
            _Float16 whi, wlo;
            split_f16(w, whi, wlo);
            o2[((c * 2 + 0) * 64 + lane) * 8 + j] = whi;
            o2[((c * 2 + 1) * 64 + lane) * 8 + j] = wlo;
        }
    }
    // ---- h1 tables: bit-identical to R6's conv1 (fmaf(+-1,w,acc) chain,
    //      same tap order, fast_tanh, split_f16) ----
    const float* w0g = W0 + layer * 144;
    const float* b0g = B0 + layer * 16;
    _Float16* ot = ws + 20480 + layer * 1536;
    for (int e = tid; e < 48; e += 256) {
        int sel = (e >= 32);
        int bits = sel ? (e - 32) : e;
        const int wtE[5] = {0, 2, 4, 6, 8};   // taps (0,0)(0,2)(1,1)(2,0)(2,2)
        const int wtO[4] = {1, 3, 5, 7};      // taps (0,1)(1,0)(1,2)(2,1)
        for (int ch = 0; ch < 16; ++ch) {
            float u = b0g[ch];
            if (!sel) {
                #pragma unroll
                for (int t = 0; t < 5; ++t) {
                    float s = ((bits >> t) & 1) ? 1.0f : -1.0f;
                    u = fmaf(s, w0g[wtE[t] * 16 + ch], u);
                }
            } else {
                #pragma unroll
                for (int t = 0; t < 4; ++t) {
                    float s = ((bits >> t) & 1) ? 1.0f : -1.0f;
                    u = fmaf(s, w0g[wtO[t] * 16 + ch], u);
                }
            }
            _Float16 hi, lo;
            split_f16(fast_tanh(u), hi, lo);
            ot[e * 32 + ch]      = hi;
            ot[e * 32 + 16 + ch] = lo;
        }
    }
}

__global__ __launch_bounds__(256, 4)
void discrete_flow_layer(const float* x_in,
                         float* x_out,
                         const _Float16* __restrict__ wfr,  // conv2 fragments
                         const _Float16* __restrict__ tbl,  // h1 table
                         const float* __restrict__ b1g,     // (16)
                         const float* __restrict__ w2g,     // (3,3,16,1)
                         const float* __restrict__ b2g,     // (1)
                         int parityA, int writeA)
{
    __shared__ __align__(16) _Float16 s_h1[400 * 40];   // aliased by s_h2
    __shared__ __align__(16) float    s_in[484];
    float* s_h2 = (float*)s_h1;                          // [ci][325] after barrier

    const int tid  = threadIdx.x;
    const int lane = tid & 63;
    const int wv   = tid >> 6;
    const int tile = blockIdx.x;
    const int b    = blockIdx.y;
    const int r0 = (tile >> 2) * TILE;
    const int c0 = (tile & 3) * TILE;
    const float* xb = x_in + (size_t)b * (LSZ * LSZ);

    // ---- prefetch conv2 weight fragments + bias (global, L2-hot) ----
    f16x8 Bh[5], Bl[5];
    #pragma unroll
    for (int c = 0; c < 5; ++c) {
        Bh[c] = *(const f16x8*)&wfr[((c * 2 + 0) * 64 + lane) * 8];
        Bl[c] = *(const f16x8*)&wfr[((c * 2 + 1) * 64 + lane) * 8];
    }
    const float b1v = b1g[lane & 15];

    // ---- phase 0: stage masked input tile (22x22, wrap) ----
    for (int idx = tid; idx < 484; idx += 256) {
        int r = idx / 22, c = idx % 22;
        int gr = (r0 + r - 3) & 63;
        int gc = (c0 + c - 3) & 63;
        float v = xb[gr * 64 + gc];
        s_in[idx] = (((gr + gc) & 1) == parityA) ? v : 0.0f;
    }
    __syncthreads();

    // ---- phase 1: h1 by pattern-table lookup ----
    for (int pp = tid; pp < 400; pp += 256) {
        int g  = (pp >= 200);
        int pi = pp - g * 200;
        int ry = pi / 10;
        int rx = 2 * (pi % 10) + ((ry ^ g) & 1);
        int base = ry * 22 + rx;
        int sel = g ^ parityA;
        int idx = 0;
        if (sel == 0) {                        // even-sum taps, 32 patterns
            const int off[5] = {0, 2, 23, 44, 46};
            #pragma unroll
            for (int t = 0; t < 5; ++t)
                idx |= (s_in[base + off[t]] > 0.0f) << t;
        } else {                               // odd-sum taps, 16 patterns
            const int off[4] = {1, 22, 24, 45};
            #pragma unroll
            for (int t = 0; t < 4; ++t)
                idx |= (s_in[base + off[t]] > 0.0f) << t;
        }
        const f16x8* row = (const f16x8*)&tbl[(sel ? 1024 : 0) + idx * 32];
        f16x8* hp = (f16x8*)&s_h1[(ry * 20 + rx) * 40];
        hp[0] = row[0]; hp[1] = row[1]; hp[2] = row[2]; hp[3] = row[3];
    }
    __syncthreads();

    // ---- phase 2: conv2 MFMA (M=324, N=16, K=144->160); D -> registers ----
    float Cs[6][8];
    {
        const int m0 = lane & 15, q = lane >> 4;
        const int qh = q >> 1, ql = q & 1;
        const int T0 = 0, T1 = 40, T2 = 80, T3 = 800, T4 = 840,
                  T5 = 880, T6 = 1600, T7 = 1640, T8 = 1680, T9 = 1680;
        #pragma unroll
        for (int s = 0; s < 6; ++s) {
            int mt = wv + s * 4;
            if (mt < 21) {
                int m_abs = mt * 16 + m0;
                if (m_abs > 323) m_abs = 323;      // clamped rows discarded later
                int oy = m_abs / 18, ox = m_abs % 18;
                int abase = (oy * 20 + ox) * 40 + ql * 8;
                f32x4 C0 = {0.f, 0.f, 0.f, 0.f};
                f32x4 C1 = {0.f, 0.f, 0.f, 0.f};
                int off;
                f16x8 A0, A1;
                #define CONV2_STEP(cc, TA, TB)                                        \
                    off = qh ? (TB) : (TA);                                           \
                    A0 = *(const f16x8*)&s_h1[abase + off];                           \
                    A1 = *(const f16x8*)&s_h1[abase + off + 16];                      \
                    C0 = __builtin_amdgcn_mfma_f32_16x16x32_f16(A0, Bh[cc], C0, 0, 0, 0); \
                    C1 = __builtin_amdgcn_mfma_f32_16x16x32_f16(A0, Bl[cc], C1, 0, 0, 0); \
                    C1 = __builtin_amdgcn_mfma_f32_16x16x32_f16(A1, Bh[cc], C1, 0, 0, 0);
                CONV2_STEP(0, T0, T1)
                CONV2_STEP(1, T2, T3)
                CONV2_STEP(2, T4, T5)
                CONV2_STEP(3, T6, T7)
                CONV2_STEP(4, T8, T9)
                #undef CONV2_STEP
                #pragma unroll
                for (int r = 0; r < 4; ++r) { Cs[s][r] = C0[r]; Cs[s][4 + r] = C1[r]; }
            }
        }
    }
    __syncthreads();   // ALL h1 reads complete -> safe to overwrite (h2 alias)

    // ---- phase 3: epilogue, bit-identical h2 values, plane-major f32 ----
    {
        const int m0 = lane & 15, q = lane >> 4;
        #pragma unroll
        for (int s = 0; s < 6; ++s) {
            int mt = wv + s * 4;
            if (mt < 21) {
                #pragma unroll
                for (int r = 0; r < 4; ++r) {
                    int m_out = mt * 16 + q * 4 + r;   // D row = m
                    if (m_out < 324) {
                        float val = Cs[s][r] + Cs[s][4 + r] * (1.0f / 2048.0f) + b1v;
                        s_h2[m0 * 325 + m_out] = fast_tanh(val);   // D col = co = m0
                    }
                }
            }
        }
    }
    __syncthreads();

    // ---- phase 4: conv3 (fp32 VALU, R8 verbatim) + sign update ----
    {
        int p = tid;
        int ry = p >> 4, rx = p & 15;
        float acc = b2g[0];
        #pragma unroll
        for (int tap = 0; tap < 9; ++tap) {
            int kh = tap / 3, kw = tap % 3;
            int hp = (ry + kh) * 18 + rx + kw;
            const float* w = &w2g[tap * 16];
            #pragma unroll
            for (int ci = 0; ci < 16; ++ci)
                acc = fmaf(s_h2[ci * 325 + hp], w[ci], acc);
        }
        int gr = r0 + ry, gc = c0 + rx;
        size_t site = (size_t)b * (LSZ * LSZ) + gr * 64 + gc;
        bool isB = (((gr + gc) & 1) != parityA);
        float xv = x_in[site];
        if (isB) {
            float m = (acc > 0.0f) ? 1.0f : ((acc < 0.0f) ? -1.0f : 0.0f);
            x_out[site] = xv * m;
        } else if (writeA) {
            x_out[site] = xv;
        }
    }
}

extern "C" void kernel_launch(void* const* d_in, const int* in_sizes, int n_in,
                              void* d_out, int out_size, void* d_ws, size_t ws_size,
                              hipStream_t stream) {
    const float* z  = (const float*)d_in[0];
    const float* W0 = (const float*)d_in[1];
    const float* B0 = (const float*)d_in[2];
    const float* W1 = (const float*)d_in[3];
    const float* B1 = (const float*)d_in[4];
    const float* W2 = (const float*)d_in[5];
    const float* B2 = (const float*)d_in[6];
    float* out = (float*)d_out;
    _Float16* ws = (_Float16*)d_ws;   // 53,248 B used

    prep<<<dim3(4), 256, 0, stream>>>(W0, B0, W1, ws);

    dim3 grid(16, 1024);
    for (int layer = 0; layer < 4; ++layer) {
        const float* xin = (layer == 0) ? z : out;
        int writeA = (layer == 0) ? 1 : 0;
        int parityA = layer & 1;
        discrete_flow_layer<<<grid, 256, 0, stream>>>(
            xin, out,
            ws + layer * 5120,
            ws + 20480 + layer * 1536,
            B1 + layer * 16,
            W2 + layer * 144,
            B2 + layer * 1,
            parityA, writeA);
    }
}

// Round 10
// 601.036 us; speedup vs baseline: 5.4343x; 1.0660x over previous
//
#include <hip/hip_runtime.h>

#define LSZ 64
#define TILE 16

typedef _Float16 f16x8 __attribute__((ext_vector_type(8)));
typedef float    f32x4 __attribute__((ext_vector_type(4)));

// LDS plan (33,936 B -> 4 blocks/CU):
//  s_h1: 400 pos x 40 f16 ([hi x16][lo x16][pad 8]) = 32,000 B
//        ALIASED by s_h2 (f32 position-major [pos][20], 324x20x4 = 25,920 B)
//        after conv2; conv2 D staged in registers across the barrier.
//  s_in: 484 f32 = 1,936 B (separate; live through phase 1 only)
//
// d_ws (f16 units): [0)      conv2 frags 4 x 5120
//                   [20480)  h1 tables   4 x 1536  (48 entries x [hi16][lo16])
//
// NUMERICS RULE (R7 post-mortem): sign-decision margin is tiny. Everything
// feeding the logit (table entries, conv2 split-MFMA, h2 f32 values, conv3
// fp32 fmaf chain incl. ORDER) must stay bit-identical to the proven pipeline.
// R10 changes LDS layout/instruction selection only.

__device__ __forceinline__ float fast_tanh(float x) {
    float ax = __builtin_fabsf(x);
    float t  = __builtin_amdgcn_exp2f(ax * -2.885390081777927f);
    float r  = (1.0f - t) * __builtin_amdgcn_rcpf(1.0f + t);
    return __builtin_copysignf(r, x);
}

// split x into f16 hi + f16 lo*2048; hi flushed if f16-subnormal (MFMA-safe)
__device__ __forceinline__ void split_f16(float x, _Float16& hi, _Float16& lo) {
    float h0 = (float)(_Float16)x;
    if (__builtin_fabsf(h0) < 6.104e-5f) h0 = 0.0f;
    hi = (_Float16)h0;
    lo = (_Float16)((x - h0) * 2048.0f);
}

__global__ void prep(const float* __restrict__ W0, const float* __restrict__ B0,
                     const float* __restrict__ W1, _Float16* __restrict__ ws) {
    const int layer = blockIdx.x, tid = threadIdx.x;
    // ---- conv2 weight fragments (k = tap*16+ci, padded 144->160) ----
    const float* w1g = W1 + layer * 2304;
    _Float16* o2 = ws + layer * 5120;
    for (int e = tid; e < 320; e += 256) {
        int c = e >> 6, lane = e & 63;
        int q = lane >> 4, co = lane & 15;
        #pragma unroll
        for (int j = 0; j < 8; ++j) {
            int k = c * 32 + q * 8 + j;
            float w = (k < 144) ? w1g[k * 16 + co] : 0.0f;
            _Float16 whi, wlo;
            split_f16(w, whi, wlo);
            o2[((c * 2 + 0) * 64 + lane) * 8 + j] = whi;
            o2[((c * 2 + 1) * 64 + lane) * 8 + j] = wlo;
        }
    }
    // ---- h1 tables: bit-identical to R6's conv1 (fmaf(+-1,w,acc) chain,
    //      same tap order, fast_tanh, split_f16) ----
    const float* w0g = W0 + layer * 144;
    const float* b0g = B0 + layer * 16;
    _Float16* ot = ws + 20480 + layer * 1536;
    for (int e = tid; e < 48; e += 256) {
        int sel = (e >= 32);
        int bits = sel ? (e - 32) : e;
        const int wtE[5] = {0, 2, 4, 6, 8};   // taps (0,0)(0,2)(1,1)(2,0)(2,2)
        const int wtO[4] = {1, 3, 5, 7};      // taps (0,1)(1,0)(1,2)(2,1)
        for (int ch = 0; ch < 16; ++ch) {
            float u = b0g[ch];
            if (!sel) {
                #pragma unroll
                for (int t = 0; t < 5; ++t) {
                    float s = ((bits >> t) & 1) ? 1.0f : -1.0f;
                    u = fmaf(s, w0g[wtE[t] * 16 + ch], u);
                }
            } else {
                #pragma unroll
                for (int t = 0; t < 4; ++t) {
                    float s = ((bits >> t) & 1) ? 1.0f : -1.0f;
                    u = fmaf(s, w0g[wtO[t] * 16 + ch], u);
                }
            }
            _Float16 hi, lo;
            split_f16(fast_tanh(u), hi, lo);
            ot[e * 32 + ch]      = hi;
            ot[e * 32 + 16 + ch] = lo;
        }
    }
}

__global__ __launch_bounds__(256, 4)
void discrete_flow_layer(const float* x_in,
                         float* x_out,
                         const _Float16* __restrict__ wfr,  // conv2 fragments
                         const _Float16* __restrict__ tbl,  // h1 table
                         const float* __restrict__ b1g,     // (16)
                         const float* __restrict__ w2g,     // (3,3,16,1)
                         const float* __restrict__ b2g,     // (1)
                         int parityA, int writeA)
{
    __shared__ __align__(16) _Float16 s_h1[400 * 40];   // aliased by s_h2
    __shared__ __align__(16) float    s_in[484];
    float* s_h2 = (float*)s_h1;                          // [pos][20] after barrier

    const int tid  = threadIdx.x;
    const int lane = tid & 63;
    const int wv   = tid >> 6;
    const int tile = blockIdx.x;
    const int b    = blockIdx.y;
    const int r0 = (tile >> 2) * TILE;
    const int c0 = (tile & 3) * TILE;
    const float* xb = x_in + (size_t)b * (LSZ * LSZ);

    // ---- prefetch conv2 weight fragments + bias (global, L2-hot) ----
    f16x8 Bh[5], Bl[5];
    #pragma unroll
    for (int c = 0; c < 5; ++c) {
        Bh[c] = *(const f16x8*)&wfr[((c * 2 + 0) * 64 + lane) * 8];
        Bl[c] = *(const f16x8*)&wfr[((c * 2 + 1) * 64 + lane) * 8];
    }
    const float b1v = b1g[lane & 15];

    // ---- phase 0: stage masked input tile (22x22, wrap) ----
    for (int idx = tid; idx < 484; idx += 256) {
        int r = idx / 22, c = idx % 22;
        int gr = (r0 + r - 3) & 63;
        int gc = (c0 + c - 3) & 63;
        float v = xb[gr * 64 + gc];
        s_in[idx] = (((gr + gc) & 1) == parityA) ? v : 0.0f;
    }
    __syncthreads();

    // ---- phase 1: h1 by pattern-table lookup ----
    for (int pp = tid; pp < 400; pp += 256) {
        int g  = (pp >= 200);
        int pi = pp - g * 200;
        int ry = pi / 10;
        int rx = 2 * (pi % 10) + ((ry ^ g) & 1);
        int base = ry * 22 + rx;
        int sel = g ^ parityA;
        int idx = 0;
        if (sel == 0) {                        // even-sum taps, 32 patterns
            const int off[5] = {0, 2, 23, 44, 46};
            #pragma unroll
            for (int t = 0; t < 5; ++t)
                idx |= (s_in[base + off[t]] > 0.0f) << t;
        } else {                               // odd-sum taps, 16 patterns
            const int off[4] = {1, 22, 24, 45};
            #pragma unroll
            for (int t = 0; t < 4; ++t)
                idx |= (s_in[base + off[t]] > 0.0f) << t;
        }
        const f16x8* row = (const f16x8*)&tbl[(sel ? 1024 : 0) + idx * 32];
        f16x8* hp = (f16x8*)&s_h1[(ry * 20 + rx) * 40];
        hp[0] = row[0]; hp[1] = row[1]; hp[2] = row[2]; hp[3] = row[3];
    }
    __syncthreads();

    // ---- phase 2: conv2 MFMA (M=324, N=16, K=144->160); D -> registers ----
    float Cs[6][8];
    {
        const int m0 = lane & 15, q = lane >> 4;
        const int qh = q >> 1, ql = q & 1;
        const int T0 = 0, T1 = 40, T2 = 80, T3 = 800, T4 = 840,
                  T5 = 880, T6 = 1600, T7 = 1640, T8 = 1680, T9 = 1680;
        #pragma unroll
        for (int s = 0; s < 6; ++s) {
            int mt = wv + s * 4;
            if (mt < 21) {
                int m_abs = mt * 16 + m0;
                if (m_abs > 323) m_abs = 323;      // clamped rows discarded later
                int oy = m_abs / 18, ox = m_abs % 18;
                int abase = (oy * 20 + ox) * 40 + ql * 8;
                f32x4 C0 = {0.f, 0.f, 0.f, 0.f};
                f32x4 C1 = {0.f, 0.f, 0.f, 0.f};
                int off;
                f16x8 A0, A1;
                #define CONV2_STEP(cc, TA, TB)                                        \
                    off = qh ? (TB) : (TA);                                           \
                    A0 = *(const f16x8*)&s_h1[abase + off];                           \
                    A1 = *(const f16x8*)&s_h1[abase + off + 16];                      \
                    C0 = __builtin_amdgcn_mfma_f32_16x16x32_f16(A0, Bh[cc], C0, 0, 0, 0); \
                    C1 = __builtin_amdgcn_mfma_f32_16x16x32_f16(A0, Bl[cc], C1, 0, 0, 0); \
                    C1 = __builtin_amdgcn_mfma_f32_16x16x32_f16(A1, Bh[cc], C1, 0, 0, 0);
                CONV2_STEP(0, T0, T1)
                CONV2_STEP(1, T2, T3)
                CONV2_STEP(2, T4, T5)
                CONV2_STEP(3, T6, T7)
                CONV2_STEP(4, T8, T9)
                #undef CONV2_STEP
                #pragma unroll
                for (int r = 0; r < 4; ++r) { Cs[s][r] = C0[r]; Cs[s][4 + r] = C1[r]; }
            }
        }
    }
    __syncthreads();   // ALL h1 reads complete -> safe to overwrite (h2 alias)

    // ---- phase 3: epilogue, bit-identical h2 values, position-major f32 ----
    {
        const int m0 = lane & 15, q = lane >> 4;
        #pragma unroll
        for (int s = 0; s < 6; ++s) {
            int mt = wv + s * 4;
            if (mt < 21) {
                #pragma unroll
                for (int r = 0; r < 4; ++r) {
                    int m_out = mt * 16 + q * 4 + r;   // D row = m
                    if (m_out < 324) {
                        float val = Cs[s][r] + Cs[s][4 + r] * (1.0f / 2048.0f) + b1v;
                        s_h2[m_out * 20 + m0] = fast_tanh(val);   // D col = ci = m0
                    }
                }
            }
        }
    }
    __syncthreads();

    // ---- phase 4: conv3 (fp32 VALU, R4-proven b128 form) + sign update ----
    // fmaf ORDER identical to R8/R9: tap ascending, ci 0..15 ascending.
    {
        int p = tid;
        int ry = p >> 4, rx = p & 15;
        float acc = b2g[0];
        #pragma unroll
        for (int tap = 0; tap < 9; ++tap) {
            int kh = tap / 3, kw = tap % 3;
            const float* hv = &s_h2[((ry + kh) * 18 + rx + kw) * 20];
            float4 v0 = *(const float4*)&hv[0];
            float4 v1 = *(const float4*)&hv[4];
            float4 v2 = *(const float4*)&hv[8];
            float4 v3 = *(const float4*)&hv[12];
            float v[16] = {v0.x, v0.y, v0.z, v0.w, v1.x, v1.y, v1.z, v1.w,
                           v2.x, v2.y, v2.z, v2.w, v3.x, v3.y, v3.z, v3.w};
            const float* w = &w2g[tap * 16];
            #pragma unroll
            for (int ci = 0; ci < 16; ++ci)
                acc = fmaf(v[ci], w[ci], acc);
        }
        int gr = r0 + ry, gc = c0 + rx;
        size_t site = (size_t)b * (LSZ * LSZ) + gr * 64 + gc;
        bool isB = (((gr + gc) & 1) != parityA);
        float xv = x_in[site];
        if (isB) {
            float m = (acc > 0.0f) ? 1.0f : ((acc < 0.0f) ? -1.0f : 0.0f);
            x_out[site] = xv * m;
        } else if (writeA) {
            x_out[site] = xv;
        }
    }
}

extern "C" void kernel_launch(void* const* d_in, const int* in_sizes, int n_in,
                              void* d_out, int out_size, void* d_ws, size_t ws_size,
                              hipStream_t stream) {
    const float* z  = (const float*)d_in[0];
    const float* W0 = (const float*)d_in[1];
    const float* B0 = (const float*)d_in[2];
    const float* W1 = (const float*)d_in[3];
    const float* B1 = (const float*)d_in[4];
    const float* W2 = (const float*)d_in[5];
    const float* B2 = (const float*)d_in[6];
    float* out = (float*)d_out;
    _Float16* ws = (_Float16*)d_ws;   // 53,248 B used

    prep<<<dim3(4), 256, 0, stream>>>(W0, B0, W1, ws);

    dim3 grid(16, 1024);
    for (int layer = 0; layer < 4; ++layer) {
        const float* xin = (layer == 0) ? z : out;
        int writeA = (layer == 0) ? 1 : 0;
        int parityA = layer & 1;
        discrete_flow_layer<<<grid, 256, 0, stream>>>(
            xin, out,
            ws + layer * 5120,
            ws + 20480 + layer * 1536,
            B1 + layer * 16,
            W2 + layer * 144,
            B2 + layer * 1,
            parityA, writeA);
    }
}